// Round 18
// baseline (134.602 us; speedup 1.0000x reference)
//
#include <hip/hip_runtime.h>
#include <math.h>

#define NN 8192
#define KDIM 256
#define DD 64
#define NB 4096
#define NBLK 128
#define NTHR 512
#define RPB 64           // rows per block
#define RPW 8            // rows per wave
#define CH 32            // sorted elements per chunk
#define NCH 256          // chunks (= NBLK*2)
#define LRALPHA 0.2f

__device__ __forceinline__ unsigned f2k(float f) {
    unsigned u = __float_as_uint(f);
    return u ^ ((u >> 31) ? 0xFFFFFFFFu : 0x80000000u);
}
__device__ __forceinline__ float k2f(unsigned k) {
    return __uint_as_float((k & 0x80000000u) ? (k ^ 0x80000000u) : ~k);
}
__device__ __forceinline__ unsigned bucket_of(unsigned key, unsigned kmin, float scale) {
    unsigned d = key - kmin;
    unsigned b = (unsigned)((float)d * scale);
    return b > (NB - 1) ? (NB - 1) : b;
}

// MALL-coherent bypass ops (PROVEN R10/R15/R17): relaxed agent-scope atomics ->
// global_load/store sc0 sc1 (L1/L2 bypass). BATCH-ISSUE loads. Do NOT use plain
// cached loads on cross-block data (R8/R9: +80us replay coherence-probe penalty).
// Do NOT use all-poll full barriers (R14: 256x poll contention).
__device__ __forceinline__ void  cstf(float* p, float v) { __hip_atomic_store(p, v, __ATOMIC_RELAXED, __HIP_MEMORY_SCOPE_AGENT); }
__device__ __forceinline__ float cldf(const float* p)    { return __hip_atomic_load((float*)p, __ATOMIC_RELAXED, __HIP_MEMORY_SCOPE_AGENT); }
__device__ __forceinline__ unsigned cldu(const unsigned* p) { return __hip_atomic_load((unsigned*)p, __ATOMIC_RELAXED, __HIP_MEMORY_SCOPE_AGENT); }
__device__ __forceinline__ void cstu(unsigned* p, unsigned v) { __hip_atomic_store(p, v, __ATOMIC_RELAXED, __HIP_MEMORY_SCOPE_AGENT); }

// Fence-free two-stage FULL grid barrier (proven R5/R7/R10).
__device__ __forceinline__ void gridbar(unsigned* flags, unsigned* rel, unsigned phase) {
    asm volatile("s_waitcnt vmcnt(0)" ::: "memory");
    __syncthreads();
    const int t = threadIdx.x;
    if (blockIdx.x == 0) {
        if (t == 0)
            cstu(&flags[0], phase);
        if (t < NBLK) {
            while (cldu(&flags[t]) < phase)
                __builtin_amdgcn_s_sleep(1);
        }
        __syncthreads();
        if (t == 0)
            cstu(rel, phase);
    } else {
        if (t == 0) {
            cstu(&flags[blockIdx.x], phase);
            while (cldu(rel) < phase)
                __builtin_amdgcn_s_sleep(1);
        }
        __syncthreads();
    }
}

__global__ __launch_bounds__(NTHR, 2) void k_fused(
    const float* __restrict__ h, const float* __restrict__ W,
    const float* __restrict__ a, float* __restrict__ out,
    float* Wh2g, float* sv, float* wnv, float* wpv, float* sg,
    float* cs_neg, float* cs_pos, float* cs_sn, float* cs_sp,
    float* PN, float* SP, float* PNs, float* SPs,
    int* cnt, unsigned* flags, unsigned* rel, unsigned* done)
{
    __shared__ int      ls_bstart[NB + 1];     // persists P1 -> P4
    __shared__ float    ls_wh1[RPB];
    __shared__ float    ls_wh2[RPB];
    __shared__ unsigned ls_ra[8], ls_rb[8];
    __shared__ int      ls_wsum[8];
    __shared__ float    ls_cs[8][2 * DD];      // P2 reduce / P3 scan scratch
    __shared__ float    ls_css[16];
    __shared__ float    ls_M2, ls_scale;
    __shared__ unsigned ls_kmin;

    const int t = threadIdx.x, bid = blockIdx.x;
    const int wv = t >> 6, lane = t & 63;
    const int rowBase = bid * RPB;

    // ================= P0: GEMM (8 rows/wave); rows live in registers ======
    float myrow[RPW];
    {
        const int r0 = rowBase + wv * RPW;
        float acc[RPW];
        #pragma unroll
        for (int i = 0; i < RPW; ++i) acc[i] = 0.f;
        #pragma unroll 2
        for (int k4 = 0; k4 < KDIM / 4; ++k4) {
            float w0 = W[(4 * k4 + 0) * DD + lane];
            float w1 = W[(4 * k4 + 1) * DD + lane];
            float w2 = W[(4 * k4 + 2) * DD + lane];
            float w3 = W[(4 * k4 + 3) * DD + lane];
            #pragma unroll
            for (int i = 0; i < RPW; ++i) {
                float4 hv = *(const float4*)(h + (size_t)(r0 + i) * KDIM + 4 * k4);
                acc[i] = fmaf(hv.x, w0, acc[i]);
                acc[i] = fmaf(hv.y, w1, acc[i]);
                acc[i] = fmaf(hv.z, w2, acc[i]);
                acc[i] = fmaf(hv.w, w3, acc[i]);
            }
        }
        float a1 = a[lane], a2 = a[DD + lane];
        #pragma unroll
        for (int i = 0; i < RPW; ++i) {
            myrow[i] = acc[i];
            float r1 = acc[i] * a1, r2 = acc[i] * a2;
            #pragma unroll
            for (int off = 32; off > 0; off >>= 1) {
                r1 += __shfl_xor(r1, off, 64);
                r2 += __shfl_xor(r2, off, 64);
            }
            if (lane == 0) {
                cstf(&Wh2g[r0 + i], r2);
                ls_wh1[wv * RPW + i] = r1;
                ls_wh2[wv * RPW + i] = r2;
            }
        }
    }
    gridbar(flags, rel, 1);

    // ================= P1: redundant minmax+hist+scan (LDS) + scatter =================
    for (int i = t; i < NB; i += NTHR) ls_bstart[i] = 0;
    float v16[16];
    #pragma unroll
    for (int q = 0; q < 16; ++q)                    // batch-issue 16 bypass loads
        v16[q] = cldf(&Wh2g[t + q * NTHR]);
    {
        unsigned lmin = 0xFFFFFFFFu, lmax = 0u;
        #pragma unroll
        for (int q = 0; q < 16; ++q) {
            unsigned k = f2k(v16[q]);
            lmin = min(lmin, k); lmax = max(lmax, k);
        }
        #pragma unroll
        for (int off = 32; off > 0; off >>= 1) {
            lmin = min(lmin, (unsigned)__shfl_xor((int)lmin, off, 64));
            lmax = max(lmax, (unsigned)__shfl_xor((int)lmax, off, 64));
        }
        if (lane == 0) { ls_ra[wv] = lmin; ls_rb[wv] = lmax; }
    }
    __syncthreads();
    if (t == 0) {
        unsigned mn = ls_ra[0], mx = ls_rb[0];
        for (int i = 1; i < 8; ++i) { mn = min(mn, ls_ra[i]); mx = max(mx, ls_rb[i]); }
        ls_kmin = mn;
        ls_scale = (float)NB / ((float)(mx - mn) + 1.0f);
        ls_M2 = k2f(mx);
    }
    __syncthreads();
    const unsigned kmin = ls_kmin;
    const float scale = ls_scale;
    const float M2 = ls_M2;

    #pragma unroll
    for (int q = 0; q < 16; ++q)
        atomicAdd(&ls_bstart[bucket_of(f2k(v16[q]), kmin, scale)], 1);
    __syncthreads();
    {
        int s[8]; int tot = 0;
        #pragma unroll
        for (int j = 0; j < 8; ++j) { s[j] = ls_bstart[8 * t + j]; tot += s[j]; }
        int x = tot;
        #pragma unroll
        for (int off = 1; off < 64; off <<= 1) {
            int y = __shfl_up(x, off, 64);
            if (lane >= off) x += y;
        }
        if (lane == 63) ls_wsum[wv] = x;
        __syncthreads();
        int woff = 0;
        for (int w2 = 0; w2 < wv; ++w2) woff += ls_wsum[w2];
        int acc = woff + x - tot;
        #pragma unroll
        for (int j = 0; j < 8; ++j) { ls_bstart[8 * t + j] = acc; acc += s[j]; }
        if (t == 0) ls_bstart[NB] = NN;
    }
    __syncthreads();
    // scatter: lanes 0-7 issue the 8 cursor RMWs concurrently; rows from registers
    {
        int posl = 0;
        if (lane < RPW) {
            unsigned b = bucket_of(f2k(ls_wh2[wv * RPW + lane]), kmin, scale);
            posl = ls_bstart[b] + atomicAdd(&cnt[b], 1);
        }
        #pragma unroll
        for (int i = 0; i < RPW; ++i) {
            int lr = wv * RPW + i;
            float x = ls_wh2[lr];
            int pos = __shfl(posl, i, 64);
            cstf(&sg[(size_t)pos * DD + lane], myrow[i]);
            if (lane == 0) {
                cstf(&sv[pos], x);
                cstf(&wnv[pos], expf(LRALPHA * (x - M2)));   // <= 1
                cstf(&wpv[pos], expf(x - M2));               // <= 1
            }
        }
    }
    gridbar(flags, rel, 2);

    // ================= P2: chunk sums — block owns chunks 2*bid and 2*bid+1 ==========
    #pragma unroll
    for (int cc = 0; cc < 2; ++cc) {
        int c = bid * 2 + cc;
        int base = c * CH + wv * 4;
        float g4[4], wn4[4], wp4[4];
        #pragma unroll
        for (int kk = 0; kk < 4; ++kk) {            // batch-issue 12 loads
            int k = base + kk;
            g4[kk]  = cldf(&sg[(size_t)k * DD + lane]);
            wn4[kk] = cldf(&wnv[k]);
            wp4[kk] = cldf(&wpv[k]);
        }
        float an = 0.f, ap = 0.f, sn = 0.f, sp = 0.f;
        #pragma unroll
        for (int kk = 0; kk < 4; ++kk) {
            an = fmaf(wn4[kk], g4[kk], an); ap = fmaf(wp4[kk], g4[kk], ap);
            sn += wn4[kk]; sp += wp4[kk];
        }
        ls_cs[wv][lane] = an; ls_cs[wv][DD + lane] = ap;
        if (lane == 0) { ls_css[wv] = sn; ls_css[8 + wv] = sp; }
        __syncthreads();
        if (wv == 0) {
            float s = 0.f;
            #pragma unroll
            for (int w2 = 0; w2 < 8; ++w2) s += ls_cs[w2][lane];
            cstf(&cs_neg[c * DD + lane], s);
            if (lane == 0) { float ss = 0.f; for (int w2 = 0; w2 < 8; ++w2) ss += ls_css[w2]; cstf(&cs_sn[c], ss); }
        } else if (wv == 1) {
            float s = 0.f;
            #pragma unroll
            for (int w2 = 0; w2 < 8; ++w2) s += ls_cs[w2][DD + lane];
            cstf(&cs_pos[c * DD + lane], s);
            if (lane == 0) { float ss = 0.f; for (int w2 = 0; w2 < 8; ++w2) ss += ls_css[8 + w2]; cstf(&cs_sp[c], ss); }
        }
        __syncthreads();                            // ls_cs reused next iteration
    }
    // ---- arrival-only sync: publish "my cs_* stores visible"; only blocks 0-2 poll ----
    asm volatile("s_waitcnt vmcnt(0)" ::: "memory");
    __syncthreads();
    if (t == 0)
        cstu(&flags[bid], 3u);

    // ================= P3: blocks 0-2 poll arrivals + scan; others skip waiting =======
    if (bid == 0) {
        if (t < NBLK) { while (cldu(&flags[t]) < 3u) __builtin_amdgcn_s_sleep(1); }
        __syncthreads();
        // exclusive prefix of neg-weighted chunk vectors -> PN[0..256]
        const int c0 = wv * 32;
        float v[32];
        #pragma unroll
        for (int j = 0; j < 32; ++j) v[j] = cldf(&cs_neg[(c0 + j) * DD + lane]);  // batch
        float tot = 0.f;
        #pragma unroll
        for (int j = 0; j < 32; ++j) tot += v[j];
        ls_cs[wv][lane] = tot;
        __syncthreads();
        float acc = 0.f;
        for (int w2 = 0; w2 < wv; ++w2) acc += ls_cs[w2][lane];
        #pragma unroll
        for (int j = 0; j < 32; ++j) { cstf(&PN[(c0 + j) * DD + lane], acc); acc += v[j]; }
        if (wv == 7) cstf(&PN[NCH * DD + lane], acc);
        asm volatile("s_waitcnt vmcnt(0)" ::: "memory");
        __syncthreads();
        if (t == 0) cstu(&done[0], 1u);
    } else if (bid == 1) {
        if (t < NBLK) { while (cldu(&flags[t]) < 3u) __builtin_amdgcn_s_sleep(1); }
        __syncthreads();
        // inclusive suffix of pos-weighted chunk vectors -> SP[0..256]
        const int c0 = wv * 32;
        float v[32];
        #pragma unroll
        for (int j = 0; j < 32; ++j) v[j] = cldf(&cs_pos[(c0 + j) * DD + lane]);  // batch
        float tot = 0.f;
        #pragma unroll
        for (int j = 0; j < 32; ++j) tot += v[j];
        ls_cs[wv][lane] = tot;
        __syncthreads();
        float acc = 0.f;
        for (int w2 = wv + 1; w2 < 8; ++w2) acc += ls_cs[w2][lane];
        #pragma unroll
        for (int j = 31; j >= 0; --j) { acc += v[j]; cstf(&SP[(c0 + j) * DD + lane], acc); }
        if (wv == 7) cstf(&SP[NCH * DD + lane], 0.f);
        asm volatile("s_waitcnt vmcnt(0)" ::: "memory");
        __syncthreads();
        if (t == 0) cstu(&done[1], 1u);
    } else if (bid == 2) {
        if (t < NBLK) { while (cldu(&flags[t]) < 3u) __builtin_amdgcn_s_sleep(1); }
        __syncthreads();
        if (wv == 0) {          // scalar prefix
            float s[4];
            #pragma unroll
            for (int j = 0; j < 4; ++j) s[j] = cldf(&cs_sn[4 * lane + j]);
            float tot = s[0] + s[1] + s[2] + s[3];
            float x = tot;
            #pragma unroll
            for (int off = 1; off < 64; off <<= 1) {
                float y = __shfl_up(x, off, 64);
                if (lane >= off) x += y;
            }
            float acc = x - tot;
            #pragma unroll
            for (int j = 0; j < 4; ++j) { cstf(&PNs[4 * lane + j], acc); acc += s[j]; }
            if (lane == 63) cstf(&PNs[NCH], acc);
        } else if (wv == 1) {   // scalar suffix
            float s[4];
            #pragma unroll
            for (int j = 0; j < 4; ++j) s[j] = cldf(&cs_sp[4 * lane + j]);
            float tot = s[0] + s[1] + s[2] + s[3];
            float x = tot;
            #pragma unroll
            for (int off = 1; off < 64; off <<= 1) {
                float y = __shfl_down(x, off, 64);
                if (lane < 64 - off) x += y;
            }
            float acc = x - tot;   // sum over lanes > lane
            #pragma unroll
            for (int j = 3; j >= 0; --j) { acc += s[j]; cstf(&SPs[4 * lane + j], acc); }
            if (lane == 63) cstf(&SPs[NCH], 0.f);
        }
        asm volatile("s_waitcnt vmcnt(0)" ::: "memory");
        __syncthreads();
        if (t == 0) cstu(&done[2], 1u);
    }

    // ---- correction precompute (all blocks; overlaps blocks 0-2's scans) ----
    int c0fA[RPW], c1eA[RPW];
    float cnA[RPW], dnA[RPW], cpA[RPW], dpA[RPW];
    #pragma unroll
    for (int i = 0; i < RPW; ++i) {
        float tt = -ls_wh1[wv * RPW + i];
        unsigned kt = f2k(tt);
        int p0 = 0, p1 = 0;
        if (kt >= kmin) {
            unsigned b = bucket_of(kt, kmin, scale);
            p0 = ls_bstart[b]; p1 = ls_bstart[b + 1];
        }
        int c0f = p0 >> 5, c1e = (p1 + 31) >> 5;     // CH = 32
        c0fA[i] = c0f; c1eA[i] = c1e;
        float nn_ = 0.f, dn_ = 0.f, np_ = 0.f, dp_ = 0.f;
        for (int base2 = c0f * CH; base2 < c1e * CH; base2 += 8) {
            float sv8[8], wn8[8], wp8[8], g8[8];
            #pragma unroll
            for (int jj = 0; jj < 8; ++jj) {        // batch-issue 32 loads
                int k = base2 + jj;
                sv8[jj] = cldf(&sv[k]);
                wn8[jj] = cldf(&wnv[k]);
                wp8[jj] = cldf(&wpv[k]);
                g8[jj]  = cldf(&sg[(size_t)k * DD + lane]);
            }
            #pragma unroll
            for (int jj = 0; jj < 8; ++jj) {
                if (sv8[jj] <= tt) { nn_ = fmaf(wn8[jj], g8[jj], nn_); dn_ += wn8[jj]; }
                else               { np_ = fmaf(wp8[jj], g8[jj], np_); dp_ += wp8[jj]; }
            }
        }
        cnA[i] = nn_; dnA[i] = dn_; cpA[i] = np_; dpA[i] = dp_;
    }

    // ---- one-way sync: wait for the 3 scan producers only ----
    if (t < 3) { while (cldu(&done[t]) < 1u) __builtin_amdgcn_s_sleep(1); }
    __syncthreads();

    // ================= P4: finalize — batched headers + math only =================
    float pnA[RPW], spA[RPW], pnsA[RPW], spsA[RPW];
    #pragma unroll
    for (int i = 0; i < RPW; ++i) {                 // batch-issue 32 header loads
        pnA[i]  = cldf(&PN[c0fA[i] * DD + lane]);
        spA[i]  = cldf(&SP[c1eA[i] * DD + lane]);
        pnsA[i] = cldf(&PNs[c0fA[i]]);
        spsA[i] = cldf(&SPs[c1eA[i]]);
    }
    #pragma unroll
    for (int i = 0; i < RPW; ++i) {
        int row = rowBase + wv * RPW + i;
        float w1 = ls_wh1[wv * RPW + i];
        float z = w1 + M2;                          // max_j (Wh1_i + Wh2_j)
        float m = (z >= 0.f) ? z : LRALPHA * z;     // lrelu(z) = exact row max
        float c1 = expf(z - m);                     // exponent <= 0
        float c2 = expf(LRALPHA * z - m);           // exponent <= 0
        float num = c2 * (pnA[i] + cnA[i]) + c1 * (spA[i] + cpA[i]);
        float den = c2 * (pnsA[i] + dnA[i]) + c1 * (spsA[i] + dpA[i]);
        float r = num / den;
        out[(size_t)row * DD + lane] = (r > 0.f) ? r : expm1f(r);   // elu
    }
}

extern "C" void kernel_launch(void* const* d_in, const int* in_sizes, int n_in,
                              void* d_out, int out_size, void* d_ws, size_t ws_size,
                              hipStream_t stream)
{
    const float* h = (const float*)d_in[0];
    // d_in[1] = adj (bool, unused by the reference computation)
    const float* W = (const float*)d_in[2];
    const float* a = (const float*)d_in[3];
    float* out = (float*)d_out;
    float* ws = (float*)d_ws;

    float* Wh2g   = ws;                              // NN
    float* sv     = Wh2g + NN;                       // NN
    float* wnv    = sv + NN;                         // NN
    float* wpv    = wnv + NN;                        // NN
    float* sg     = wpv + NN;                        // NN*DD (sorted Wh rows)
    float* cs_neg = sg + (size_t)NN * DD;            // NCH*DD
    float* cs_pos = cs_neg + NCH * DD;               // NCH*DD
    float* cs_sn  = cs_pos + NCH * DD;               // NCH
    float* cs_sp  = cs_sn + NCH;                     // NCH
    float* PN     = cs_sp + NCH;                     // (NCH+1)*DD
    float* SP     = PN + (NCH + 1) * DD;             // (NCH+1)*DD
    float* PNs    = SP + (NCH + 1) * DD;             // NCH+1 (pad 320)
    float* SPs    = PNs + 320;                       // NCH+1 (pad 320)
    unsigned* flags = (unsigned*)(SPs + 320);        // NBLK
    unsigned* rel   = flags + NBLK;                  // 1 (pad 64)
    unsigned* done  = rel + 64;                      // 3 (pad 64)
    int*   cnt    = (int*)(done + 64);               // NB cursors (must start at 0)

    // zero flags + rel + done + cnt in one captured async memset
    hipMemsetAsync(flags, 0, (NBLK + 64 + 64 + NB) * sizeof(unsigned), stream);
    k_fused<<<NBLK, NTHR, 0, stream>>>(h, W, a, out,
        Wh2g, sv, wnv, wpv, sg,
        cs_neg, cs_pos, cs_sn, cs_sp,
        PN, SP, PNs, SPs,
        cnt, flags, rel, done);
}

// Round 19
// 111.223 us; speedup vs baseline: 1.2102x; 1.2102x over previous
//
#include <hip/hip_runtime.h>
#include <math.h>

#define NN 8192
#define KDIM 256
#define DD 64
#define NB 4096
#define NBLK 256
#define NTHR 512
#define RPB 32           // rows per block
#define CH 32            // sorted elements per chunk (= rows per block)
#define NCH 256          // chunks
#define LRALPHA 0.2f

__device__ __forceinline__ unsigned f2k(float f) {
    unsigned u = __float_as_uint(f);
    return u ^ ((u >> 31) ? 0xFFFFFFFFu : 0x80000000u);
}
__device__ __forceinline__ float k2f(unsigned k) {
    return __uint_as_float((k & 0x80000000u) ? (k ^ 0x80000000u) : ~k);
}
__device__ __forceinline__ unsigned bucket_of(unsigned key, unsigned kmin, float scale) {
    unsigned d = key - kmin;
    unsigned b = (unsigned)((float)d * scale);
    return b > (NB - 1) ? (NB - 1) : b;
}

// MALL-coherent bypass ops (PROVEN R10/R15/R17): relaxed agent-scope atomics ->
// global_load/store sc0 sc1 (L1/L2 bypass). BATCH-ISSUE loads — atomics stay in
// program order, so a batch's USE blocks the NEXT batch's issue: minimize the number
// of dependent batches on the critical path. Do NOT use plain cached loads on
// cross-block data (R8/R9). Do NOT use all-poll full barriers (R14). Do NOT halve
// the grid (R18: half the CUs = 1.5x slower).
__device__ __forceinline__ void  cstf(float* p, float v) { __hip_atomic_store(p, v, __ATOMIC_RELAXED, __HIP_MEMORY_SCOPE_AGENT); }
__device__ __forceinline__ float cldf(const float* p)    { return __hip_atomic_load((float*)p, __ATOMIC_RELAXED, __HIP_MEMORY_SCOPE_AGENT); }
__device__ __forceinline__ unsigned cldu(const unsigned* p) { return __hip_atomic_load((unsigned*)p, __ATOMIC_RELAXED, __HIP_MEMORY_SCOPE_AGENT); }
__device__ __forceinline__ void cstu(unsigned* p, unsigned v) { __hip_atomic_store(p, v, __ATOMIC_RELAXED, __HIP_MEMORY_SCOPE_AGENT); }

// Fence-free two-stage FULL grid barrier (proven R5/R7/R10).
__device__ __forceinline__ void gridbar(unsigned* flags, unsigned* rel, unsigned phase) {
    asm volatile("s_waitcnt vmcnt(0)" ::: "memory");
    __syncthreads();
    const int t = threadIdx.x;
    if (blockIdx.x == 0) {
        if (t == 0)
            cstu(&flags[0], phase);
        if (t < NBLK) {
            while (cldu(&flags[t]) < phase)
                __builtin_amdgcn_s_sleep(1);
        }
        __syncthreads();
        if (t == 0)
            cstu(rel, phase);
    } else {
        if (t == 0) {
            cstu(&flags[blockIdx.x], phase);
            while (cldu(rel) < phase)
                __builtin_amdgcn_s_sleep(1);
        }
        __syncthreads();
    }
}

__global__ __launch_bounds__(NTHR, 2) void k_fused(
    const float* __restrict__ h, const float* __restrict__ W,
    const float* __restrict__ a, float* __restrict__ out,
    float* Wh2g, float* sv, float* sg,
    float* cs_neg, float* cs_pos, float* cs_sn, float* cs_sp,
    float* PN, float* SP, float* PNs, float* SPs,
    int* cnt, unsigned* flags, unsigned* rel, unsigned* done)
{
    __shared__ int      ls_bstart[NB + 1];     // persists P1 -> P4
    __shared__ float    ls_wh1[RPB];
    __shared__ float    ls_wh2[RPB];
    __shared__ unsigned ls_ra[8], ls_rb[8];
    __shared__ int      ls_wsum[8];
    __shared__ float    ls_cs[8][2 * DD];      // P2 reduce / P3 scan scratch
    __shared__ float    ls_css[16];
    __shared__ float    ls_M2, ls_scale;
    __shared__ unsigned ls_kmin;

    const int t = threadIdx.x, bid = blockIdx.x;
    const int wv = t >> 6, lane = t & 63;
    const int rowBase = bid * RPB;

    // ================= P0: GEMM; rows live in registers until scatter ======
    float myrow[4];
    {
        const int r0 = rowBase + wv * 4;
        float acc0 = 0.f, acc1 = 0.f, acc2 = 0.f, acc3 = 0.f;
        #pragma unroll 2
        for (int k4 = 0; k4 < KDIM / 4; ++k4) {
            float w0 = W[(4 * k4 + 0) * DD + lane];
            float w1 = W[(4 * k4 + 1) * DD + lane];
            float w2 = W[(4 * k4 + 2) * DD + lane];
            float w3 = W[(4 * k4 + 3) * DD + lane];
            float4 h0 = *(const float4*)(h + (size_t)(r0 + 0) * KDIM + 4 * k4);
            float4 h1 = *(const float4*)(h + (size_t)(r0 + 1) * KDIM + 4 * k4);
            float4 h2 = *(const float4*)(h + (size_t)(r0 + 2) * KDIM + 4 * k4);
            float4 h3 = *(const float4*)(h + (size_t)(r0 + 3) * KDIM + 4 * k4);
            acc0 = fmaf(h0.x, w0, acc0); acc0 = fmaf(h0.y, w1, acc0);
            acc0 = fmaf(h0.z, w2, acc0); acc0 = fmaf(h0.w, w3, acc0);
            acc1 = fmaf(h1.x, w0, acc1); acc1 = fmaf(h1.y, w1, acc1);
            acc1 = fmaf(h1.z, w2, acc1); acc1 = fmaf(h1.w, w3, acc1);
            acc2 = fmaf(h2.x, w0, acc2); acc2 = fmaf(h2.y, w1, acc2);
            acc2 = fmaf(h2.z, w2, acc2); acc2 = fmaf(h2.w, w3, acc2);
            acc3 = fmaf(h3.x, w0, acc3); acc3 = fmaf(h3.y, w1, acc3);
            acc3 = fmaf(h3.z, w2, acc3); acc3 = fmaf(h3.w, w3, acc3);
        }
        myrow[0] = acc0; myrow[1] = acc1; myrow[2] = acc2; myrow[3] = acc3;
        float a1 = a[lane], a2 = a[DD + lane];
        #pragma unroll
        for (int i = 0; i < 4; ++i) {
            float r1 = myrow[i] * a1, r2 = myrow[i] * a2;
            #pragma unroll
            for (int off = 32; off > 0; off >>= 1) {
                r1 += __shfl_xor(r1, off, 64);
                r2 += __shfl_xor(r2, off, 64);
            }
            if (lane == 0) {
                cstf(&Wh2g[r0 + i], r2);
                ls_wh1[wv * 4 + i] = r1;
                ls_wh2[wv * 4 + i] = r2;
            }
        }
    }
    gridbar(flags, rel, 1);

    // ================= P1: redundant minmax+hist+scan (LDS) + scatter =================
    for (int i = t; i < NB; i += NTHR) ls_bstart[i] = 0;
    float v16[16];
    #pragma unroll
    for (int q = 0; q < 16; ++q)                    // batch-issue 16 bypass loads
        v16[q] = cldf(&Wh2g[t + q * NTHR]);
    {
        unsigned lmin = 0xFFFFFFFFu, lmax = 0u;
        #pragma unroll
        for (int q = 0; q < 16; ++q) {
            unsigned k = f2k(v16[q]);
            lmin = min(lmin, k); lmax = max(lmax, k);
        }
        #pragma unroll
        for (int off = 32; off > 0; off >>= 1) {
            lmin = min(lmin, (unsigned)__shfl_xor((int)lmin, off, 64));
            lmax = max(lmax, (unsigned)__shfl_xor((int)lmax, off, 64));
        }
        if (lane == 0) { ls_ra[wv] = lmin; ls_rb[wv] = lmax; }
    }
    __syncthreads();
    if (t == 0) {
        unsigned mn = ls_ra[0], mx = ls_rb[0];
        for (int i = 1; i < 8; ++i) { mn = min(mn, ls_ra[i]); mx = max(mx, ls_rb[i]); }
        ls_kmin = mn;
        ls_scale = (float)NB / ((float)(mx - mn) + 1.0f);
        ls_M2 = k2f(mx);
    }
    __syncthreads();
    const unsigned kmin = ls_kmin;
    const float scale = ls_scale;
    const float M2 = ls_M2;

    #pragma unroll
    for (int q = 0; q < 16; ++q)
        atomicAdd(&ls_bstart[bucket_of(f2k(v16[q]), kmin, scale)], 1);
    __syncthreads();
    {
        int s[8]; int tot = 0;
        #pragma unroll
        for (int j = 0; j < 8; ++j) { s[j] = ls_bstart[8 * t + j]; tot += s[j]; }
        int x = tot;
        #pragma unroll
        for (int off = 1; off < 64; off <<= 1) {
            int y = __shfl_up(x, off, 64);
            if (lane >= off) x += y;
        }
        if (lane == 63) ls_wsum[wv] = x;
        __syncthreads();
        int woff = 0;
        for (int w2 = 0; w2 < wv; ++w2) woff += ls_wsum[w2];
        int acc = woff + x - tot;
        #pragma unroll
        for (int j = 0; j < 8; ++j) { ls_bstart[8 * t + j] = acc; acc += s[j]; }
        if (t == 0) ls_bstart[NB] = NN;
    }
    __syncthreads();
    // scatter: lanes 0-3 issue the 4 cursor RMWs concurrently; rows from registers.
    // wn/wp are NOT stored — consumers recompute from sv (expf deterministic).
    {
        int posl = 0;
        if (lane < 4) {
            unsigned b = bucket_of(f2k(ls_wh2[wv * 4 + lane]), kmin, scale);
            posl = ls_bstart[b] + atomicAdd(&cnt[b], 1);
        }
        #pragma unroll
        for (int i = 0; i < 4; ++i) {
            int lr = wv * 4 + i;
            float x = ls_wh2[lr];
            int pos = __shfl(posl, i, 64);
            cstf(&sg[(size_t)pos * DD + lane], myrow[i]);
            if (lane == 0) cstf(&sv[pos], x);
        }
    }
    gridbar(flags, rel, 2);

    // ================= P2: chunk sums — chunk bid; wn/wp recomputed from sv ==========
    {
        int base = bid * CH + wv * 4;
        float g4[4], sv4[4];
        #pragma unroll
        for (int kk = 0; kk < 4; ++kk) {            // batch-issue 8 loads
            int k = base + kk;
            g4[kk]  = cldf(&sg[(size_t)k * DD + lane]);
            sv4[kk] = cldf(&sv[k]);
        }
        float an = 0.f, ap = 0.f, sn = 0.f, sp = 0.f;
        #pragma unroll
        for (int kk = 0; kk < 4; ++kk) {
            float wn = expf(LRALPHA * (sv4[kk] - M2));   // <= 1
            float wp = expf(sv4[kk] - M2);               // <= 1
            an = fmaf(wn, g4[kk], an); ap = fmaf(wp, g4[kk], ap);
            sn += wn; sp += wp;
        }
        ls_cs[wv][lane] = an; ls_cs[wv][DD + lane] = ap;
        if (lane == 0) { ls_css[wv] = sn; ls_css[8 + wv] = sp; }
        __syncthreads();
        if (wv == 0) {
            float s = 0.f;
            #pragma unroll
            for (int w2 = 0; w2 < 8; ++w2) s += ls_cs[w2][lane];
            cstf(&cs_neg[bid * DD + lane], s);
            if (lane == 0) { float ss = 0.f; for (int w2 = 0; w2 < 8; ++w2) ss += ls_css[w2]; cstf(&cs_sn[bid], ss); }
        } else if (wv == 1) {
            float s = 0.f;
            #pragma unroll
            for (int w2 = 0; w2 < 8; ++w2) s += ls_cs[w2][DD + lane];
            cstf(&cs_pos[bid * DD + lane], s);
            if (lane == 0) { float ss = 0.f; for (int w2 = 0; w2 < 8; ++w2) ss += ls_css[8 + w2]; cstf(&cs_sp[bid], ss); }
        }
    }
    // ---- arrival-only sync: publish "my cs_* stores visible"; only blocks 0-2 poll ----
    asm volatile("s_waitcnt vmcnt(0)" ::: "memory");
    __syncthreads();
    if (t == 0)
        cstu(&flags[bid], 3u);

    // ================= P3: blocks 0-2 poll arrivals + scan; others skip waiting =======
    if (bid == 0) {
        if (t < NBLK) { while (cldu(&flags[t]) < 3u) __builtin_amdgcn_s_sleep(1); }
        __syncthreads();
        const int c0 = wv * 32;
        float v[32];
        #pragma unroll
        for (int j = 0; j < 32; ++j) v[j] = cldf(&cs_neg[(c0 + j) * DD + lane]);  // batch
        float tot = 0.f;
        #pragma unroll
        for (int j = 0; j < 32; ++j) tot += v[j];
        ls_cs[wv][lane] = tot;
        __syncthreads();
        float acc = 0.f;
        for (int w2 = 0; w2 < wv; ++w2) acc += ls_cs[w2][lane];
        #pragma unroll
        for (int j = 0; j < 32; ++j) { cstf(&PN[(c0 + j) * DD + lane], acc); acc += v[j]; }
        if (wv == 7) cstf(&PN[NCH * DD + lane], acc);
        asm volatile("s_waitcnt vmcnt(0)" ::: "memory");
        __syncthreads();
        if (t == 0) cstu(&done[0], 1u);
    } else if (bid == 1) {
        if (t < NBLK) { while (cldu(&flags[t]) < 3u) __builtin_amdgcn_s_sleep(1); }
        __syncthreads();
        const int c0 = wv * 32;
        float v[32];
        #pragma unroll
        for (int j = 0; j < 32; ++j) v[j] = cldf(&cs_pos[(c0 + j) * DD + lane]);  // batch
        float tot = 0.f;
        #pragma unroll
        for (int j = 0; j < 32; ++j) tot += v[j];
        ls_cs[wv][lane] = tot;
        __syncthreads();
        float acc = 0.f;
        for (int w2 = wv + 1; w2 < 8; ++w2) acc += ls_cs[w2][lane];
        #pragma unroll
        for (int j = 31; j >= 0; --j) { acc += v[j]; cstf(&SP[(c0 + j) * DD + lane], acc); }
        if (wv == 7) cstf(&SP[NCH * DD + lane], 0.f);
        asm volatile("s_waitcnt vmcnt(0)" ::: "memory");
        __syncthreads();
        if (t == 0) cstu(&done[1], 1u);
    } else if (bid == 2) {
        if (t < NBLK) { while (cldu(&flags[t]) < 3u) __builtin_amdgcn_s_sleep(1); }
        __syncthreads();
        if (wv == 0) {          // scalar prefix
            float s[4];
            #pragma unroll
            for (int j = 0; j < 4; ++j) s[j] = cldf(&cs_sn[4 * lane + j]);
            float tot = s[0] + s[1] + s[2] + s[3];
            float x = tot;
            #pragma unroll
            for (int off = 1; off < 64; off <<= 1) {
                float y = __shfl_up(x, off, 64);
                if (lane >= off) x += y;
            }
            float acc = x - tot;
            #pragma unroll
            for (int j = 0; j < 4; ++j) { cstf(&PNs[4 * lane + j], acc); acc += s[j]; }
            if (lane == 63) cstf(&PNs[NCH], acc);
        } else if (wv == 1) {   // scalar suffix
            float s[4];
            #pragma unroll
            for (int j = 0; j < 4; ++j) s[j] = cldf(&cs_sp[4 * lane + j]);
            float tot = s[0] + s[1] + s[2] + s[3];
            float x = tot;
            #pragma unroll
            for (int off = 1; off < 64; off <<= 1) {
                float y = __shfl_down(x, off, 64);
                if (lane < 64 - off) x += y;
            }
            float acc = x - tot;   // sum over lanes > lane
            #pragma unroll
            for (int j = 3; j >= 0; --j) { acc += s[j]; cstf(&SPs[4 * lane + j], acc); }
            if (lane == 63) cstf(&SPs[NCH], 0.f);
        }
        asm volatile("s_waitcnt vmcnt(0)" ::: "memory");
        __syncthreads();
        if (t == 0) cstu(&done[2], 1u);
    }

    // ---- correction precompute: 4 rows INTERLEAVED per super-batch so round trips
    //      = max_i(batches_i), not sum_i(batches_i). wn/wp recomputed from sv. ----
    int c0f4[4], c1e4[4], nb4[4];
    float tt4[4];
    int maxnb = 0;
    #pragma unroll
    for (int i = 0; i < 4; ++i) {
        float tt = -ls_wh1[wv * 4 + i];
        tt4[i] = tt;
        unsigned kt = f2k(tt);
        int p0 = 0, p1 = 0;
        if (kt >= kmin) {
            unsigned b = bucket_of(kt, kmin, scale);
            p0 = ls_bstart[b]; p1 = ls_bstart[b + 1];
        }
        int c0f = p0 >> 5, c1e = (p1 + 31) >> 5;     // CH = 32
        c0f4[i] = c0f; c1e4[i] = c1e;
        nb4[i] = (c1e - c0f) * (CH / 8);             // 8-elem batches (window % 8 == 0)
        maxnb = max(maxnb, nb4[i]);
    }
    float cn4[4] = {0,0,0,0}, dn4[4] = {0,0,0,0}, cp4[4] = {0,0,0,0}, dp4[4] = {0,0,0,0};
    for (int b = 0; b < maxnb; ++b) {
        float sv8[4][8], g8[4][8];
        #pragma unroll
        for (int i = 0; i < 4; ++i) {               // batch-issue up to 64 loads (all rows)
            if (b < nb4[i]) {
                int k0 = c0f4[i] * CH + b * 8;
                #pragma unroll
                for (int jj = 0; jj < 8; ++jj) {
                    sv8[i][jj] = cldf(&sv[k0 + jj]);
                    g8[i][jj]  = cldf(&sg[(size_t)(k0 + jj) * DD + lane]);
                }
            }
        }
        #pragma unroll
        for (int i = 0; i < 4; ++i) {
            if (b < nb4[i]) {
                float tt = tt4[i];
                #pragma unroll
                for (int jj = 0; jj < 8; ++jj) {
                    float svv = sv8[i][jj], g = g8[i][jj];
                    if (svv <= tt) {
                        float wn = expf(LRALPHA * (svv - M2));
                        cn4[i] = fmaf(wn, g, cn4[i]); dn4[i] += wn;
                    } else {
                        float wp = expf(svv - M2);
                        cp4[i] = fmaf(wp, g, cp4[i]); dp4[i] += wp;
                    }
                }
            }
        }
    }

    // ---- one-way sync: wait for the 3 scan producers only ----
    if (t < 3) { while (cldu(&done[t]) < 1u) __builtin_amdgcn_s_sleep(1); }
    __syncthreads();

    // ================= P4: finalize — batched headers + math only =================
    float pn4[4], sp4[4], pns4[4], sps4[4];
    #pragma unroll
    for (int i = 0; i < 4; ++i) {                   // batch-issue 16 header loads
        pn4[i]  = cldf(&PN[c0f4[i] * DD + lane]);
        sp4[i]  = cldf(&SP[c1e4[i] * DD + lane]);
        pns4[i] = cldf(&PNs[c0f4[i]]);
        sps4[i] = cldf(&SPs[c1e4[i]]);
    }
    #pragma unroll
    for (int i = 0; i < 4; ++i) {
        int row = rowBase + wv * 4 + i;
        float w1 = ls_wh1[wv * 4 + i];
        float z = w1 + M2;                          // max_j (Wh1_i + Wh2_j)
        float m = (z >= 0.f) ? z : LRALPHA * z;     // lrelu(z) = exact row max
        float c1 = expf(z - m);                     // exponent <= 0
        float c2 = expf(LRALPHA * z - m);           // exponent <= 0
        float num = c2 * (pn4[i] + cn4[i]) + c1 * (sp4[i] + cp4[i]);
        float den = c2 * (pns4[i] + dn4[i]) + c1 * (sps4[i] + dp4[i]);
        float r = num / den;
        out[(size_t)row * DD + lane] = (r > 0.f) ? r : expm1f(r);   // elu
    }
}

extern "C" void kernel_launch(void* const* d_in, const int* in_sizes, int n_in,
                              void* d_out, int out_size, void* d_ws, size_t ws_size,
                              hipStream_t stream)
{
    const float* h = (const float*)d_in[0];
    // d_in[1] = adj (bool, unused by the reference computation)
    const float* W = (const float*)d_in[2];
    const float* a = (const float*)d_in[3];
    float* out = (float*)d_out;
    float* ws = (float*)d_ws;

    float* Wh2g   = ws;                              // NN
    float* sv     = Wh2g + NN;                       // NN
    float* sg     = sv + NN;                         // NN*DD (sorted Wh rows)
    float* cs_neg = sg + (size_t)NN * DD;            // NCH*DD
    float* cs_pos = cs_neg + NCH * DD;               // NCH*DD
    float* cs_sn  = cs_pos + NCH * DD;               // NCH
    float* cs_sp  = cs_sn + NCH;                     // NCH
    float* PN     = cs_sp + NCH;                     // (NCH+1)*DD
    float* SP     = PN + (NCH + 1) * DD;             // (NCH+1)*DD
    float* PNs    = SP + (NCH + 1) * DD;             // NCH+1 (pad 320)
    float* SPs    = PNs + 320;                       // NCH+1 (pad 320)
    unsigned* flags = (unsigned*)(SPs + 320);        // NBLK
    unsigned* rel   = flags + NBLK;                  // 1 (pad 64)
    unsigned* done  = rel + 64;                      // 3 (pad 64)
    int*   cnt    = (int*)(done + 64);               // NB cursors (must start at 0)

    // zero flags + rel + done + cnt in one captured async memset
    hipMemsetAsync(flags, 0, (NBLK + 64 + 64 + NB) * sizeof(unsigned), stream);
    k_fused<<<NBLK, NTHR, 0, stream>>>(h, W, a, out,
        Wh2g, sv, sg,
        cs_neg, cs_pos, cs_sn, cs_sp,
        PN, SP, PNs, SPs,
        cnt, flags, rel, done);
}

// Round 20
// 89.447 us; speedup vs baseline: 1.5048x; 1.2434x over previous
//
#include <hip/hip_runtime.h>
#include <math.h>

#define NN 8192
#define KDIM 256
#define DD 64
#define NB 4096
#define NBLK 256
#define NTHR 512
#define RPB 32           // rows per block
#define CH 32            // sorted elements per chunk (= rows per block)
#define NCH 256          // chunks
#define LRALPHA 0.2f

__device__ __forceinline__ unsigned f2k(float f) {
    unsigned u = __float_as_uint(f);
    return u ^ ((u >> 31) ? 0xFFFFFFFFu : 0x80000000u);
}
__device__ __forceinline__ float k2f(unsigned k) {
    return __uint_as_float((k & 0x80000000u) ? (k ^ 0x80000000u) : ~k);
}
__device__ __forceinline__ unsigned bucket_of(unsigned key, unsigned kmin, float scale) {
    unsigned d = key - kmin;
    unsigned b = (unsigned)((float)d * scale);
    return b > (NB - 1) ? (NB - 1) : b;
}

// MALL-coherent bypass ops (PROVEN R10/R15/R17): relaxed agent-scope atomics ->
// global_load/store sc0 sc1 (L1/L2 bypass). BATCH-ISSUE loads. Do NOT use plain
// cached loads on cross-block data (R8/R9: +80us replay coherence-probe penalty).
// Do NOT use all-poll full barriers (R14). Do NOT halve the grid (R18). Do NOT
// interleave correction rows into one super-batch (R19: +64 VGPR live state, +21us).
__device__ __forceinline__ void  cstf(float* p, float v) { __hip_atomic_store(p, v, __ATOMIC_RELAXED, __HIP_MEMORY_SCOPE_AGENT); }
__device__ __forceinline__ float cldf(const float* p)    { return __hip_atomic_load((float*)p, __ATOMIC_RELAXED, __HIP_MEMORY_SCOPE_AGENT); }
__device__ __forceinline__ unsigned cldu(const unsigned* p) { return __hip_atomic_load((unsigned*)p, __ATOMIC_RELAXED, __HIP_MEMORY_SCOPE_AGENT); }
__device__ __forceinline__ void cstu(unsigned* p, unsigned v) { __hip_atomic_store(p, v, __ATOMIC_RELAXED, __HIP_MEMORY_SCOPE_AGENT); }

// Fence-free two-stage FULL grid barrier (proven R5/R7/R10).
__device__ __forceinline__ void gridbar(unsigned* flags, unsigned* rel, unsigned phase) {
    asm volatile("s_waitcnt vmcnt(0)" ::: "memory");
    __syncthreads();
    const int t = threadIdx.x;
    if (blockIdx.x == 0) {
        if (t == 0)
            cstu(&flags[0], phase);
        if (t < NBLK) {
            while (cldu(&flags[t]) < phase)
                __builtin_amdgcn_s_sleep(1);
        }
        __syncthreads();
        if (t == 0)
            cstu(rel, phase);
    } else {
        if (t == 0) {
            cstu(&flags[blockIdx.x], phase);
            while (cldu(rel) < phase)
                __builtin_amdgcn_s_sleep(1);
        }
        __syncthreads();
    }
}

__global__ __launch_bounds__(NTHR, 2) void k_fused(
    const float* __restrict__ h, const float* __restrict__ W,
    const float* __restrict__ a, float* __restrict__ out,
    float* Wh2g, float* sv, float* wnv, float* wpv, float* sg,
    float* cs_neg, float* cs_pos, float* cs_sn, float* cs_sp,
    float* PN, float* SP, float* PNs, float* SPs,
    int* cnt, unsigned* flags, unsigned* rel, unsigned* done)
{
    __shared__ int      ls_bstart[NB + 1];     // persists P1 -> P4
    __shared__ float    ls_wh1[RPB];
    __shared__ float    ls_wh2[RPB];
    __shared__ unsigned ls_ra[8], ls_rb[8];
    __shared__ int      ls_wsum[8];
    __shared__ float    ls_cs[8][2 * DD];      // P2 reduce / P3 scan scratch
    __shared__ float    ls_css[16];
    __shared__ float    ls_M2, ls_scale;
    __shared__ unsigned ls_kmin;

    const int t = threadIdx.x, bid = blockIdx.x;
    const int wv = t >> 6, lane = t & 63;
    const int rowBase = bid * RPB;

    // ================= P0: GEMM; rows live in registers until scatter ======
    float myrow[4];
    {
        const int r0 = rowBase + wv * 4;
        float acc0 = 0.f, acc1 = 0.f, acc2 = 0.f, acc3 = 0.f;
        #pragma unroll 2
        for (int k4 = 0; k4 < KDIM / 4; ++k4) {
            float w0 = W[(4 * k4 + 0) * DD + lane];
            float w1 = W[(4 * k4 + 1) * DD + lane];
            float w2 = W[(4 * k4 + 2) * DD + lane];
            float w3 = W[(4 * k4 + 3) * DD + lane];
            float4 h0 = *(const float4*)(h + (size_t)(r0 + 0) * KDIM + 4 * k4);
            float4 h1 = *(const float4*)(h + (size_t)(r0 + 1) * KDIM + 4 * k4);
            float4 h2 = *(const float4*)(h + (size_t)(r0 + 2) * KDIM + 4 * k4);
            float4 h3 = *(const float4*)(h + (size_t)(r0 + 3) * KDIM + 4 * k4);
            acc0 = fmaf(h0.x, w0, acc0); acc0 = fmaf(h0.y, w1, acc0);
            acc0 = fmaf(h0.z, w2, acc0); acc0 = fmaf(h0.w, w3, acc0);
            acc1 = fmaf(h1.x, w0, acc1); acc1 = fmaf(h1.y, w1, acc1);
            acc1 = fmaf(h1.z, w2, acc1); acc1 = fmaf(h1.w, w3, acc1);
            acc2 = fmaf(h2.x, w0, acc2); acc2 = fmaf(h2.y, w1, acc2);
            acc2 = fmaf(h2.z, w2, acc2); acc2 = fmaf(h2.w, w3, acc2);
            acc3 = fmaf(h3.x, w0, acc3); acc3 = fmaf(h3.y, w1, acc3);
            acc3 = fmaf(h3.z, w2, acc3); acc3 = fmaf(h3.w, w3, acc3);
        }
        myrow[0] = acc0; myrow[1] = acc1; myrow[2] = acc2; myrow[3] = acc3;
        float a1 = a[lane], a2 = a[DD + lane];
        #pragma unroll
        for (int i = 0; i < 4; ++i) {
            float r1 = myrow[i] * a1, r2 = myrow[i] * a2;
            #pragma unroll
            for (int off = 32; off > 0; off >>= 1) {
                r1 += __shfl_xor(r1, off, 64);
                r2 += __shfl_xor(r2, off, 64);
            }
            if (lane == 0) {
                cstf(&Wh2g[r0 + i], r2);
                ls_wh1[wv * 4 + i] = r1;
                ls_wh2[wv * 4 + i] = r2;
            }
        }
    }
    gridbar(flags, rel, 1);

    // ================= P1: redundant minmax+hist+scan (LDS) + scatter =================
    for (int i = t; i < NB; i += NTHR) ls_bstart[i] = 0;
    float v16[16];
    #pragma unroll
    for (int q = 0; q < 16; ++q)                    // batch-issue 16 bypass loads
        v16[q] = cldf(&Wh2g[t + q * NTHR]);
    {
        unsigned lmin = 0xFFFFFFFFu, lmax = 0u;
        #pragma unroll
        for (int q = 0; q < 16; ++q) {
            unsigned k = f2k(v16[q]);
            lmin = min(lmin, k); lmax = max(lmax, k);
        }
        #pragma unroll
        for (int off = 32; off > 0; off >>= 1) {
            lmin = min(lmin, (unsigned)__shfl_xor((int)lmin, off, 64));
            lmax = max(lmax, (unsigned)__shfl_xor((int)lmax, off, 64));
        }
        if (lane == 0) { ls_ra[wv] = lmin; ls_rb[wv] = lmax; }
    }
    __syncthreads();
    if (t == 0) {
        unsigned mn = ls_ra[0], mx = ls_rb[0];
        for (int i = 1; i < 8; ++i) { mn = min(mn, ls_ra[i]); mx = max(mx, ls_rb[i]); }
        ls_kmin = mn;
        ls_scale = (float)NB / ((float)(mx - mn) + 1.0f);
        ls_M2 = k2f(mx);
    }
    __syncthreads();
    const unsigned kmin = ls_kmin;
    const float scale = ls_scale;
    const float M2 = ls_M2;

    #pragma unroll
    for (int q = 0; q < 16; ++q)
        atomicAdd(&ls_bstart[bucket_of(f2k(v16[q]), kmin, scale)], 1);
    __syncthreads();
    {
        int s[8]; int tot = 0;
        #pragma unroll
        for (int j = 0; j < 8; ++j) { s[j] = ls_bstart[8 * t + j]; tot += s[j]; }
        int x = tot;
        #pragma unroll
        for (int off = 1; off < 64; off <<= 1) {
            int y = __shfl_up(x, off, 64);
            if (lane >= off) x += y;
        }
        if (lane == 63) ls_wsum[wv] = x;
        __syncthreads();
        int woff = 0;
        for (int w2 = 0; w2 < wv; ++w2) woff += ls_wsum[w2];
        int acc = woff + x - tot;
        #pragma unroll
        for (int j = 0; j < 8; ++j) { ls_bstart[8 * t + j] = acc; acc += s[j]; }
        if (t == 0) ls_bstart[NB] = NN;
    }
    __syncthreads();
    // scatter: lanes 0-3 issue the 4 cursor RMWs concurrently; rows from registers
    {
        int posl = 0;
        if (lane < 4) {
            unsigned b = bucket_of(f2k(ls_wh2[wv * 4 + lane]), kmin, scale);
            posl = ls_bstart[b] + atomicAdd(&cnt[b], 1);
        }
        #pragma unroll
        for (int i = 0; i < 4; ++i) {
            int lr = wv * 4 + i;
            float x = ls_wh2[lr];
            int pos = __shfl(posl, i, 64);
            cstf(&sg[(size_t)pos * DD + lane], myrow[i]);
            if (lane == 0) {
                cstf(&sv[pos], x);
                cstf(&wnv[pos], expf(LRALPHA * (x - M2)));   // <= 1
                cstf(&wpv[pos], expf(x - M2));               // <= 1
            }
        }
    }
    gridbar(flags, rel, 2);

    // ================= P2: chunk sums — chunk bid = sorted rows [32*bid, 32*bid+32) ==
    {
        int base = bid * CH + wv * 4;
        float g4[4], wn4[4], wp4[4];
        #pragma unroll
        for (int kk = 0; kk < 4; ++kk) {            // batch-issue 12 loads
            int k = base + kk;
            g4[kk]  = cldf(&sg[(size_t)k * DD + lane]);
            wn4[kk] = cldf(&wnv[k]);
            wp4[kk] = cldf(&wpv[k]);
        }
        float an = 0.f, ap = 0.f, sn = 0.f, sp = 0.f;
        #pragma unroll
        for (int kk = 0; kk < 4; ++kk) {
            an = fmaf(wn4[kk], g4[kk], an); ap = fmaf(wp4[kk], g4[kk], ap);
            sn += wn4[kk]; sp += wp4[kk];
        }
        ls_cs[wv][lane] = an; ls_cs[wv][DD + lane] = ap;
        if (lane == 0) { ls_css[wv] = sn; ls_css[8 + wv] = sp; }
        __syncthreads();
        if (wv == 0) {
            float s = 0.f;
            #pragma unroll
            for (int w2 = 0; w2 < 8; ++w2) s += ls_cs[w2][lane];
            cstf(&cs_neg[bid * DD + lane], s);
            if (lane == 0) { float ss = 0.f; for (int w2 = 0; w2 < 8; ++w2) ss += ls_css[w2]; cstf(&cs_sn[bid], ss); }
        } else if (wv == 1) {
            float s = 0.f;
            #pragma unroll
            for (int w2 = 0; w2 < 8; ++w2) s += ls_cs[w2][DD + lane];
            cstf(&cs_pos[bid * DD + lane], s);
            if (lane == 0) { float ss = 0.f; for (int w2 = 0; w2 < 8; ++w2) ss += ls_css[8 + w2]; cstf(&cs_sp[bid], ss); }
        }
    }
    // ---- arrival-only sync: publish "my cs_* stores visible"; only blocks 0-2 poll ----
    asm volatile("s_waitcnt vmcnt(0)" ::: "memory");
    __syncthreads();
    if (t == 0)
        cstu(&flags[bid], 3u);

    // ================= P3: blocks 0-2 poll arrivals + scan; others skip waiting =======
    if (bid == 0) {
        if (t < NBLK) { while (cldu(&flags[t]) < 3u) __builtin_amdgcn_s_sleep(1); }
        __syncthreads();
        // exclusive prefix of neg-weighted chunk vectors -> PN[0..256]
        const int c0 = wv * 32;
        float v[32];
        #pragma unroll
        for (int j = 0; j < 32; ++j) v[j] = cldf(&cs_neg[(c0 + j) * DD + lane]);  // batch
        float tot = 0.f;
        #pragma unroll
        for (int j = 0; j < 32; ++j) tot += v[j];
        ls_cs[wv][lane] = tot;
        __syncthreads();
        float acc = 0.f;
        for (int w2 = 0; w2 < wv; ++w2) acc += ls_cs[w2][lane];
        #pragma unroll
        for (int j = 0; j < 32; ++j) { cstf(&PN[(c0 + j) * DD + lane], acc); acc += v[j]; }
        if (wv == 7) cstf(&PN[NCH * DD + lane], acc);
        asm volatile("s_waitcnt vmcnt(0)" ::: "memory");
        __syncthreads();
        if (t == 0) cstu(&done[0], 1u);
    } else if (bid == 1) {
        if (t < NBLK) { while (cldu(&flags[t]) < 3u) __builtin_amdgcn_s_sleep(1); }
        __syncthreads();
        // inclusive suffix of pos-weighted chunk vectors -> SP[0..256]
        const int c0 = wv * 32;
        float v[32];
        #pragma unroll
        for (int j = 0; j < 32; ++j) v[j] = cldf(&cs_pos[(c0 + j) * DD + lane]);  // batch
        float tot = 0.f;
        #pragma unroll
        for (int j = 0; j < 32; ++j) tot += v[j];
        ls_cs[wv][lane] = tot;
        __syncthreads();
        float acc = 0.f;
        for (int w2 = wv + 1; w2 < 8; ++w2) acc += ls_cs[w2][lane];
        #pragma unroll
        for (int j = 31; j >= 0; --j) { acc += v[j]; cstf(&SP[(c0 + j) * DD + lane], acc); }
        if (wv == 7) cstf(&SP[NCH * DD + lane], 0.f);
        asm volatile("s_waitcnt vmcnt(0)" ::: "memory");
        __syncthreads();
        if (t == 0) cstu(&done[1], 1u);
    } else if (bid == 2) {
        if (t < NBLK) { while (cldu(&flags[t]) < 3u) __builtin_amdgcn_s_sleep(1); }
        __syncthreads();
        if (wv == 0) {          // scalar prefix
            float s[4];
            #pragma unroll
            for (int j = 0; j < 4; ++j) s[j] = cldf(&cs_sn[4 * lane + j]);
            float tot = s[0] + s[1] + s[2] + s[3];
            float x = tot;
            #pragma unroll
            for (int off = 1; off < 64; off <<= 1) {
                float y = __shfl_up(x, off, 64);
                if (lane >= off) x += y;
            }
            float acc = x - tot;
            #pragma unroll
            for (int j = 0; j < 4; ++j) { cstf(&PNs[4 * lane + j], acc); acc += s[j]; }
            if (lane == 63) cstf(&PNs[NCH], acc);
        } else if (wv == 1) {   // scalar suffix
            float s[4];
            #pragma unroll
            for (int j = 0; j < 4; ++j) s[j] = cldf(&cs_sp[4 * lane + j]);
            float tot = s[0] + s[1] + s[2] + s[3];
            float x = tot;
            #pragma unroll
            for (int off = 1; off < 64; off <<= 1) {
                float y = __shfl_down(x, off, 64);
                if (lane < 64 - off) x += y;
            }
            float acc = x - tot;   // sum over lanes > lane
            #pragma unroll
            for (int j = 3; j >= 0; --j) { acc += s[j]; cstf(&SPs[4 * lane + j], acc); }
            if (lane == 63) cstf(&SPs[NCH], 0.f);
        }
        asm volatile("s_waitcnt vmcnt(0)" ::: "memory");
        __syncthreads();
        if (t == 0) cstu(&done[2], 1u);
    }

    // ---- correction precompute (all blocks; overlaps blocks 0-2's scans;
    //      depends only on post-scatter data, final since barrier 2) ----
    int c0f4[4], c1e4[4];
    float cn4[4], dn4[4], cp4[4], dp4[4];
    #pragma unroll
    for (int i = 0; i < 4; ++i) {
        float tt = -ls_wh1[wv * 4 + i];
        unsigned kt = f2k(tt);
        int p0 = 0, p1 = 0;
        if (kt >= kmin) {
            unsigned b = bucket_of(kt, kmin, scale);
            p0 = ls_bstart[b]; p1 = ls_bstart[b + 1];
        }
        int c0f = p0 >> 5, c1e = (p1 + 31) >> 5;     // CH = 32
        c0f4[i] = c0f; c1e4[i] = c1e;
        float nn_ = 0.f, dn_ = 0.f, np_ = 0.f, dp_ = 0.f;
        for (int base2 = c0f * CH; base2 < c1e * CH; base2 += 8) {
            float sv8[8], wn8[8], wp8[8], g8[8];
            #pragma unroll
            for (int jj = 0; jj < 8; ++jj) {        // batch-issue 32 loads
                int k = base2 + jj;
                sv8[jj] = cldf(&sv[k]);
                wn8[jj] = cldf(&wnv[k]);
                wp8[jj] = cldf(&wpv[k]);
                g8[jj]  = cldf(&sg[(size_t)k * DD + lane]);
            }
            #pragma unroll
            for (int jj = 0; jj < 8; ++jj) {
                if (sv8[jj] <= tt) { nn_ = fmaf(wn8[jj], g8[jj], nn_); dn_ += wn8[jj]; }
                else               { np_ = fmaf(wp8[jj], g8[jj], np_); dp_ += wp8[jj]; }
            }
        }
        cn4[i] = nn_; dn4[i] = dn_; cp4[i] = np_; dp4[i] = dp_;
    }

    // ---- one-way sync: wait for the 3 scan producers only ----
    if (t < 3) { while (cldu(&done[t]) < 1u) __builtin_amdgcn_s_sleep(1); }
    __syncthreads();

    // ================= P4: finalize — batched headers + math only =================
    float pn4[4], sp4[4], pns4[4], sps4[4];
    #pragma unroll
    for (int i = 0; i < 4; ++i) {                   // batch-issue 16 header loads
        pn4[i]  = cldf(&PN[c0f4[i] * DD + lane]);
        sp4[i]  = cldf(&SP[c1e4[i] * DD + lane]);
        pns4[i] = cldf(&PNs[c0f4[i]]);
        sps4[i] = cldf(&SPs[c1e4[i]]);
    }
    #pragma unroll
    for (int i = 0; i < 4; ++i) {
        int row = rowBase + wv * 4 + i;
        float w1 = ls_wh1[wv * 4 + i];
        float z = w1 + M2;                          // max_j (Wh1_i + Wh2_j)
        float m = (z >= 0.f) ? z : LRALPHA * z;     // lrelu(z) = exact row max
        float c1 = expf(z - m);                     // exponent <= 0
        float c2 = expf(LRALPHA * z - m);           // exponent <= 0
        float num = c2 * (pn4[i] + cn4[i]) + c1 * (sp4[i] + cp4[i]);
        float den = c2 * (pns4[i] + dn4[i]) + c1 * (sps4[i] + dp4[i]);
        float r = num / den;
        out[(size_t)row * DD + lane] = (r > 0.f) ? r : expm1f(r);   // elu
    }
}

extern "C" void kernel_launch(void* const* d_in, const int* in_sizes, int n_in,
                              void* d_out, int out_size, void* d_ws, size_t ws_size,
                              hipStream_t stream)
{
    const float* h = (const float*)d_in[0];
    // d_in[1] = adj (bool, unused by the reference computation)
    const float* W = (const float*)d_in[2];
    const float* a = (const float*)d_in[3];
    float* out = (float*)d_out;
    float* ws = (float*)d_ws;

    float* Wh2g   = ws;                              // NN
    float* sv     = Wh2g + NN;                       // NN
    float* wnv    = sv + NN;                         // NN
    float* wpv    = wnv + NN;                        // NN
    float* sg     = wpv + NN;                        // NN*DD (sorted Wh rows)
    float* cs_neg = sg + (size_t)NN * DD;            // NCH*DD
    float* cs_pos = cs_neg + NCH * DD;               // NCH*DD
    float* cs_sn  = cs_pos + NCH * DD;               // NCH
    float* cs_sp  = cs_sn + NCH;                     // NCH
    float* PN     = cs_sp + NCH;                     // (NCH+1)*DD
    float* SP     = PN + (NCH + 1) * DD;             // (NCH+1)*DD
    float* PNs    = SP + (NCH + 1) * DD;             // NCH+1 (pad 320)
    float* SPs    = PNs + 320;                       // NCH+1 (pad 320)
    unsigned* flags = (unsigned*)(SPs + 320);        // NBLK
    unsigned* rel   = flags + NBLK;                  // 1 (pad 64)
    unsigned* done  = rel + 64;                      // 3 (pad 64)
    int*   cnt    = (int*)(done + 64);               // NB cursors (must start at 0)

    // zero flags + rel + done + cnt in one captured async memset
    hipMemsetAsync(flags, 0, (NBLK + 64 + 64 + NB) * sizeof(unsigned), stream);
    k_fused<<<NBLK, NTHR, 0, stream>>>(h, W, a, out,
        Wh2g, sv, wnv, wpv, sg,
        cs_neg, cs_pos, cs_sn, cs_sp,
        PN, SP, PNs, SPs,
        cnt, flags, rel, done);
}